// Round 9
// baseline (541.520 us; speedup 1.0000x reference)
//
#include <hip/hip_runtime.h>
#include <math.h>

// ============================ DIAGNOSTIC BUILD ============================
// Same math as R7; each kernel re-executes its body REP_* times so every
// stage exceeds the harness's 40us fill dispatches and appears in rocprof
// top-5 with true per-stage counters.  t_stage = dur_us / REP_stage.
// De-instrument next round by setting all REP_* to 1 (or removing loops).
// ==========================================================================
#define REP_FRONT  16
#define REP_ATTN   12
#define REP_ROWCOL 24
#define REP_PAIR   12

// Problem constants: B=2, L=768, H=256, NH=8, HD=32
#define NL 768

typedef __attribute__((ext_vector_type(8))) short bf16x8;  // 8 bf16 = 4 VGPR
typedef __attribute__((ext_vector_type(4))) float f32x4;
typedef _Float16 h2v __attribute__((ext_vector_type(2)));

static __device__ __forceinline__ ushort f2bf(float f) {
    uint u = __float_as_uint(f);
    u += 0x7fffu + ((u >> 16) & 1u);           // round-to-nearest-even
    return (ushort)(u >> 16);
}
static __device__ __forceinline__ uint pack2(float a, float b) {
    return (uint)f2bf(a) | ((uint)f2bf(b) << 16);
}
// load 8 consecutive fp32 -> bf16x8 fragment (register-only convert)
static __device__ __forceinline__ bf16x8 load8bf(const float* p) {
    float4 a = *(const float4*)p;
    float4 b = *(const float4*)(p + 4);
    uint4 r;
    r.x = pack2(a.x, a.y); r.y = pack2(a.z, a.w);
    r.z = pack2(b.x, b.y); r.w = pack2(b.z, b.w);
    return __builtin_bit_cast(bf16x8, r);
}
// packed fp16: relu(a+b) via v_pk_add_f16 + v_pk_max_f16
static __device__ __forceinline__ uint addrelu2(uint a, uint b) {
    h2v s = __builtin_bit_cast(h2v, a) + __builtin_bit_cast(h2v, b);
    h2v z = {(_Float16)0.f, (_Float16)0.f};
    s = __builtin_elementwise_max(s, z);
    return __builtin_bit_cast(uint, s);
}
// fp32 += dot2(fp16x2, fp16x2) via v_dot2_f32_f16
static __device__ __forceinline__ float fdot2u(uint a, uint b, float c) {
#if __has_builtin(__builtin_amdgcn_fdot2)
    return __builtin_amdgcn_fdot2(__builtin_bit_cast(h2v, a),
                                  __builtin_bit_cast(h2v, b), c, false);
#else
    h2v x = __builtin_bit_cast(h2v, a), y = __builtin_bit_cast(h2v, b);
    return fmaf((float)x[1], (float)y[1], fmaf((float)x[0], (float)y[0], c));
#endif
}
static __device__ __forceinline__ float fexp2(float x) {
#if __has_builtin(__builtin_amdgcn_exp2f)
    return __builtin_amdgcn_exp2f(x);
#else
    return exp2f(x);
#endif
}

// 1/sqrt(32) * log2(e): folded into Q at write time so attn uses exp2 directly
#define QSC 0.25503487f

// ---------------------------------------------------------------------------
// front_kernel (see R7 comments; unchanged math, rep-looped).
// ---------------------------------------------------------------------------
__global__ __launch_bounds__(256) void front_kernel(
    const float* __restrict__ features, const float* __restrict__ in_proj_w,
    const float* __restrict__ in_proj_b, const float* __restrict__ out_w,
    const float* __restrict__ out_b, const float* __restrict__ w1,
    const float* __restrict__ b1,
    ushort* __restrict__ qkvb, ushort* __restrict__ vtp,
    ushort* __restrict__ WcT, float* __restrict__ bc)
{
    __shared__ float Aw[32][33];
    __shared__ float Bw[32][33];
    const int bid = blockIdx.x;
    const int t = threadIdx.x;
    for (int rep = 0; rep < REP_FRONT; ++rep) {
    asm volatile("" ::: "memory");
    if (bid < 576) {
        const int lane = t & 63, w = t >> 6;
        const int lg = lane >> 4, lc = lane & 15;
        const int u = bid * 4 + w;
        const int m0 = (u / 24) * 16, n0 = (u % 24) * 32;
        f32x4 acc[2] = {};
        #pragma unroll
        for (int k0 = 0; k0 < 256; k0 += 32) {
            bf16x8 af = load8bf(features + (size_t)(m0 + lc) * 256 + k0 + 8 * lg);
            #pragma unroll
            for (int j = 0; j < 2; ++j) {
                bf16x8 bf = load8bf(in_proj_w + (size_t)(n0 + 16 * j + lc) * 256 + k0 + 8 * lg);
                acc[j] = __builtin_amdgcn_mfma_f32_16x16x32_bf16(af, bf, acc[j], 0, 0, 0);
            }
        }
        const int bb = m0 >= 768;          // batch index (m0 is 16-aligned)
        const int seq0 = m0 - bb * 768;
        #pragma unroll
        for (int j = 0; j < 2; ++j) {
            int n = n0 + 16 * j + lc;
            float bv = in_proj_b[n];
            float sc = (n0 + 16 * j) < 256 ? QSC : 1.0f;   // wave-uniform per j
            if (n < 512) {
                #pragma unroll
                for (int ii = 0; ii < 4; ++ii)
                    qkvb[(size_t)(m0 + 4 * lg + ii) * 768 + n] =
                        f2bf((acc[j][ii] + bv) * sc);
            } else {
                int hh = (n - 512) >> 5, dd = (n - 512) & 31;
                int seqb = seq0 + 4 * lg;              // 4-aligned
                int pos = (seqb & ~31) + 8 * ((seqb >> 2) & 3) + 4 * ((seqb >> 4) & 1);
                ushort* vp = vtp + (size_t)((bb * 8 + hh) * 32 + dd) * 768 + pos;
                uint lo = pack2(acc[j][0] + bv, acc[j][1] + bv);
                uint hi = pack2(acc[j][2] + bv, acc[j][3] + bv);
                *(uint2*)vp = make_uint2(lo, hi);
            }
        }
    } else if (bid < 640) {
        const int u2 = bid - 576;
        const int k0 = (u2 & 7) * 32, c0 = (u2 >> 3) * 32;
        const float* w1x = w1 + (c0 >= 128 ? 256 * 128 : 0);
        const int cc0 = c0 & 127;
        const int tx = t & 15, ty = t >> 4;
        float acc[2][2] = {};
        for (int j0 = 0; j0 < 256; j0 += 32) {
            __syncthreads();
            for (int v = t; v < 32 * 32; v += 256) {
                int r = v >> 5, c = v & 31;
                Aw[r][c] = out_w[(size_t)(j0 + r) * 256 + k0 + c];
                Bw[r][c] = w1x[(size_t)(j0 + r) * 128 + cc0 + c];
            }
            __syncthreads();
            #pragma unroll
            for (int jj = 0; jj < 32; ++jj) {
                float a0 = Aw[jj][ty * 2], a1 = Aw[jj][ty * 2 + 1];
                float b0 = Bw[jj][tx * 2], b1v = Bw[jj][tx * 2 + 1];
                acc[0][0] = fmaf(a0, b0, acc[0][0]);
                acc[0][1] = fmaf(a0, b1v, acc[0][1]);
                acc[1][0] = fmaf(a1, b0, acc[1][0]);
                acc[1][1] = fmaf(a1, b1v, acc[1][1]);
            }
        }
        #pragma unroll
        for (int i = 0; i < 2; ++i)
            #pragma unroll
            for (int j = 0; j < 2; ++j)
                WcT[(size_t)(c0 + tx * 2 + j) * 256 + (k0 + ty * 2 + i)] = f2bf(acc[i][j]);
    } else {
        const float* w1x = w1 + (t >= 128 ? 256 * 128 : 0);
        const int cc = t & 127;
        float a = 0.f;
        #pragma unroll 8
        for (int j = 0; j < 256; ++j)
            a = fmaf(out_b[j], w1x[(size_t)j * 128 + cc], a);
        bc[t] = a + (t < 128 ? b1[cc] : 0.f);
    }
    }  // rep
}

// ---------------------------------------------------------------------------
// attn_kernel (R7 math, rep-looped).
// ---------------------------------------------------------------------------
__global__ __launch_bounds__(256) void attn_kernel(
    const ushort* __restrict__ qkvb, const ushort* __restrict__ vtp,
    ushort* __restrict__ attnb)
{
    __shared__ float Ow[4][16][33];
    __shared__ float Lw[4][16];
    const int qt = blockIdx.x, bh = blockIdx.y, b = bh >> 3, h = bh & 7;
    const int m0 = qt * 16;
    const int t = threadIdx.x, lane = t & 63, w = t >> 6;
    const int lg = lane >> 4, lc = lane & 15;
    const ushort* qbase = qkvb + (size_t)(b * NL) * 768;
    const ushort* vbase = vtp + (size_t)((b * 8 + h) * 32) * 768;

    for (int rep = 0; rep < REP_ATTN; ++rep) {
    asm volatile("" ::: "memory");
    __syncthreads();   // WAR on Ow/Lw across reps

    bf16x8 qa = *(const bf16x8*)(qbase + (size_t)(m0 + lc) * 768 + h * 32 + 8 * lg);

    f32x4 o0 = {}, o1 = {};
    float lsum = 0.f;

    for (int kt = 0; kt < 3; ++kt) {
        const int k0 = w * 192 + kt * 64;
        f32x4 s[4];
        #pragma unroll
        for (int t4 = 0; t4 < 4; ++t4) {
            bf16x8 kb = *(const bf16x8*)(qbase + (size_t)(k0 + 16 * t4 + lc) * 768
                                         + 256 + h * 32 + 8 * lg);
            f32x4 z = {};
            s[t4] = __builtin_amdgcn_mfma_f32_16x16x32_bf16(kb, qa, z, 0, 0, 0);
        }
        uint pk[4][2];
        #pragma unroll
        for (int t4 = 0; t4 < 4; ++t4) {
            float p0 = fexp2(s[t4][0]);
            float p1 = fexp2(s[t4][1]);
            float p2 = fexp2(s[t4][2]);
            float p3 = fexp2(s[t4][3]);
            lsum += (p0 + p1) + (p2 + p3);
            pk[t4][0] = pack2(p0, p1);
            pk[t4][1] = pack2(p2, p3);
        }
        #pragma unroll
        for (int c = 0; c < 2; ++c) {
            uint4 au;
            au.x = pk[2 * c][0];     au.y = pk[2 * c][1];
            au.z = pk[2 * c + 1][0]; au.w = pk[2 * c + 1][1];
            bf16x8 pa = __builtin_bit_cast(bf16x8, au);
            bf16x8 v0 = *(const bf16x8*)(vbase + (size_t)lc * 768 + k0 + 32 * c + 8 * lg);
            bf16x8 v1 = *(const bf16x8*)(vbase + (size_t)(16 + lc) * 768 + k0 + 32 * c + 8 * lg);
            o0 = __builtin_amdgcn_mfma_f32_16x16x32_bf16(pa, v0, o0, 0, 0, 0);
            o1 = __builtin_amdgcn_mfma_f32_16x16x32_bf16(pa, v1, o1, 0, 0, 0);
        }
    }
    lsum += __shfl_xor(lsum, 16);
    lsum += __shfl_xor(lsum, 32);
    #pragma unroll
    for (int i = 0; i < 4; ++i) {
        Ow[w][4 * lg + i][lc] = o0[i];
        Ow[w][4 * lg + i][16 + lc] = o1[i];
    }
    if (lg == 0) Lw[w][lc] = lsum;
    __syncthreads();
    {
        const int q = 4 * w + lg;
        float l = (Lw[0][q] + Lw[1][q]) + (Lw[2][q] + Lw[3][q]);
        float inv = 1.f / l;
        float a0 = (Ow[0][q][lc] + Ow[1][q][lc]) + (Ow[2][q][lc] + Ow[3][q][lc]);
        float a1 = (Ow[0][q][16 + lc] + Ow[1][q][16 + lc])
                 + (Ow[2][q][16 + lc] + Ow[3][q][16 + lc]);
        size_t orow = (size_t)(b * NL + m0 + q);
        attnb[orow * 256 + h * 32 + lc] = f2bf(a0 * inv);
        attnb[orow * 256 + h * 32 + 16 + lc] = f2bf(a1 * inv);
    }
    }  // rep
}

// ---------------------------------------------------------------------------
// rowcol_kernel (R7 math, rep-looped).
// ---------------------------------------------------------------------------
__global__ __launch_bounds__(256) void rowcol_kernel(
    const ushort* __restrict__ attnb, const ushort* __restrict__ WcT,
    const float* __restrict__ bc, ushort* __restrict__ rowcol)
{
    const int t = threadIdx.x, lane = t & 63, w = t >> 6;
    const int lg = lane >> 4, lc = lane & 15;
    const int u = blockIdx.x * 4 + w;          // [0,1536)
    const int m0 = (u >> 4) * 16, n0 = (u & 15) * 16;
    for (int rep = 0; rep < REP_ROWCOL; ++rep) {
    asm volatile("" ::: "memory");
    f32x4 acc = {};
    #pragma unroll
    for (int k0 = 0; k0 < 256; k0 += 32) {
        bf16x8 a = *(const bf16x8*)(attnb + (size_t)(m0 + lc) * 256 + k0 + 8 * lg);
        bf16x8 bfr = *(const bf16x8*)(WcT + (size_t)(n0 + lc) * 256 + k0 + 8 * lg);
        acc = __builtin_amdgcn_mfma_f32_16x16x32_bf16(a, bfr, acc, 0, 0, 0);
    }
    const int n = n0 + lc;
    const float bv = bc[n];
    #pragma unroll
    for (int ii = 0; ii < 4; ++ii)
        ((_Float16*)rowcol)[(size_t)(m0 + 4 * lg + ii) * 256 + n] = (_Float16)(acc[ii] + bv);
    }  // rep
}

// ---------------------------------------------------------------------------
// pairwise_kernel (R7 math, rep-looped).
// ---------------------------------------------------------------------------
__global__ __launch_bounds__(256) void pairwise_kernel(
    const ushort* __restrict__ rowcol, const float* __restrict__ w2,
    const float* __restrict__ b2, float* __restrict__ out)
{
    __shared__ __align__(16) ushort rs[32 * 136];
    __shared__ __align__(16) ushort cs[64 * 136];
    __shared__ uint w2u[64];
    const int b = blockIdx.z, i0 = blockIdx.y * 32, j0 = blockIdx.x * 64;
    const int t = threadIdx.x;
    for (int rep = 0; rep < REP_PAIR; ++rep) {
    asm volatile("" ::: "memory");
    __syncthreads();   // WAR on rs/cs across reps
    #pragma unroll
    for (int v = t; v < 512; v += 256) {
        int r = v >> 4, q = v & 15;
        *(uint4*)&rs[r * 136 + q * 8] =
            *(const uint4*)(rowcol + (size_t)(b * NL + i0 + r) * 256 + q * 8);
    }
    #pragma unroll
    for (int v = t; v < 1024; v += 256) {
        int r = v >> 4, q = v & 15;
        *(uint4*)&cs[r * 136 + q * 8] =
            *(const uint4*)(rowcol + (size_t)(b * NL + j0 + r) * 256 + 128 + q * 8);
    }
    if (t < 64) {
        float2 wv = *(const float2*)&w2[2 * t];
        h2v hw = {(_Float16)wv.x, (_Float16)wv.y};
        w2u[t] = __builtin_bit_cast(uint, hw);
    }
    __syncthreads();
    const int lane = t & 63, w = t >> 6;
    const int rg = lane >> 3, cg = lane & 7;
    const int wy = w >> 1, wx = w & 1;
    float acc[2][4] = {};
    for (int c8 = 0; c8 < 128; c8 += 8) {
        uint wu[4];
        *(uint4*)wu = *(const uint4*)&w2u[c8 >> 1];
        uint ru[2][4], cu[4][4];
        #pragma unroll
        for (int i = 0; i < 2; ++i)
            *(uint4*)ru[i] = *(const uint4*)&rs[(16 * wy + rg + 8 * i) * 136 + c8];
        #pragma unroll
        for (int j = 0; j < 4; ++j)
            *(uint4*)cu[j] = *(const uint4*)&cs[(32 * wx + cg + 8 * j) * 136 + c8];
        #pragma unroll
        for (int i = 0; i < 2; ++i)
            #pragma unroll
            for (int j = 0; j < 4; ++j) {
                float a = acc[i][j];
                #pragma unroll
                for (int p = 0; p < 4; ++p)
                    a = fdot2u(addrelu2(ru[i][p], cu[j][p]), wu[p], a);
                acc[i][j] = a;
            }
    }
    const float bb = b2[0];
    #pragma unroll
    for (int i = 0; i < 2; ++i)
        #pragma unroll
        for (int j = 0; j < 4; ++j)
            out[(size_t)(b * NL + i0 + 16 * wy + rg + 8 * i) * NL
                + j0 + 32 * wx + cg + 8 * j] = acc[i][j] + bb;
    }  // rep
}

// ---------------------------------------------------------------------------
extern "C" void kernel_launch(void* const* d_in, const int* in_sizes, int n_in,
                              void* d_out, int out_size, void* d_ws, size_t ws_size,
                              hipStream_t stream)
{
    const float* features  = (const float*)d_in[0];  // [2,768,256]
    const float* in_proj_w = (const float*)d_in[1];  // [768,256]
    const float* in_proj_b = (const float*)d_in[2];  // [768]
    const float* out_w     = (const float*)d_in[3];  // [256,256]
    const float* out_b     = (const float*)d_in[4];  // [256]
    const float* w1        = (const float*)d_in[5];  // [512,128]
    const float* b1        = (const float*)d_in[6];  // [128]
    const float* w2        = (const float*)d_in[7];  // [128,1]
    const float* b2        = (const float*)d_in[8];  // [1]
    float* out = (float*)d_out;                      // [2,768,768]

    ushort* qkvb   = (ushort*)d_ws;                  // [1536,768] bf16 (Q scaled, K)
    ushort* vtp    = qkvb + 1179648;                 // [512,768]  bf16 V^T, slot-permuted
    ushort* attnb  = vtp + 393216;                   // [1536,256] bf16
    ushort* WcT    = attnb + 393216;                 // [256,256]  bf16
    float*  bc     = (float*)(WcT + 65536);          // [256] fp32
    ushort* rowcol = (ushort*)(bc + 256);            // [1536,256] fp16

    front_kernel<<<dim3(641), 256, 0, stream>>>(
        features, in_proj_w, in_proj_b, out_w, out_b, w1, b1, qkvb, vtp, WcT, bc);
    attn_kernel<<<dim3(48, 16), 256, 0, stream>>>(qkvb, vtp, attnb);
    rowcol_kernel<<<dim3(384), 256, 0, stream>>>(attnb, WcT, bc, rowcol);
    pairwise_kernel<<<dim3(12, 24, 2), 256, 0, stream>>>(rowcol, w2, b2, out);
}

// Round 10
// 50.976 us; speedup vs baseline: 10.6230x; 10.6230x over previous
//
#include <hip/hip_runtime.h>
#include <math.h>

// Problem constants: B=2, L=768, H=256, NH=8, HD=32
#define NL 768

typedef __attribute__((ext_vector_type(8))) short bf16x8;  // 8 bf16 = 4 VGPR
typedef __attribute__((ext_vector_type(4))) float f32x4;
typedef _Float16 h2v __attribute__((ext_vector_type(2)));

static __device__ __forceinline__ ushort f2bf(float f) {
    uint u = __float_as_uint(f);
    u += 0x7fffu + ((u >> 16) & 1u);           // round-to-nearest-even
    return (ushort)(u >> 16);
}
static __device__ __forceinline__ uint pack2(float a, float b) {
    return (uint)f2bf(a) | ((uint)f2bf(b) << 16);
}
static __device__ __forceinline__ uint4 pack8(float4 a, float4 b) {
    uint4 r;
    r.x = pack2(a.x, a.y); r.y = pack2(a.z, a.w);
    r.z = pack2(b.x, b.y); r.w = pack2(b.z, b.w);
    return r;
}
// packed fp16: relu(a+b) via v_pk_add_f16 + v_pk_max_f16
static __device__ __forceinline__ uint addrelu2(uint a, uint b) {
    h2v s = __builtin_bit_cast(h2v, a) + __builtin_bit_cast(h2v, b);
    h2v z = {(_Float16)0.f, (_Float16)0.f};
    s = __builtin_elementwise_max(s, z);
    return __builtin_bit_cast(uint, s);
}
// fp32 += dot2(fp16x2, fp16x2) via v_dot2_f32_f16
static __device__ __forceinline__ float fdot2u(uint a, uint b, float c) {
#if __has_builtin(__builtin_amdgcn_fdot2)
    return __builtin_amdgcn_fdot2(__builtin_bit_cast(h2v, a),
                                  __builtin_bit_cast(h2v, b), c, false);
#else
    h2v x = __builtin_bit_cast(h2v, a), y = __builtin_bit_cast(h2v, b);
    return fmaf((float)x[1], (float)y[1], fmaf((float)x[0], (float)y[0], c));
#endif
}
static __device__ __forceinline__ float fexp2(float x) {
#if __has_builtin(__builtin_amdgcn_exp2f)
    return __builtin_amdgcn_exp2f(x);
#else
    return exp2f(x);
#endif
}

// 1/sqrt(32) * log2(e): folded into Q at write time so attn uses exp2 directly
#define QSC 0.25503487f

// XOR-swizzled element index for bf16 LDS tile with 128-element rows (256 B):
// spreads the 16-B units of 8 consecutive rows over all 32 banks.
#define SWZ(r, ce) (((((r) * 256 + (ce) * 2) ^ (((r) & 7) << 4))) >> 1)

// ---------------------------------------------------------------------------
// front_kernel, grid 353.
//  blocks [0,288):   LDS-staged bf16 GEMM, 64x64 C-tile, K in 2 halves of 128.
//    Output: n<256 -> Q (pre-scaled QSC) -> qkvb; n<512 -> K -> qkvb;
//            n>=512 -> V -> vtp[(b,h,d)][seq] slot-permuted (see R7).
//  blocks [288,352): combine_w 32x32 tile (LDS overlaid on As/Bs)
//  block 352:        combine_bias
// ---------------------------------------------------------------------------
__global__ __launch_bounds__(256) void front_kernel(
    const float* __restrict__ features, const float* __restrict__ in_proj_w,
    const float* __restrict__ in_proj_b, const float* __restrict__ out_w,
    const float* __restrict__ out_b, const float* __restrict__ w1,
    const float* __restrict__ b1,
    ushort* __restrict__ qkvb, ushort* __restrict__ vtp,
    ushort* __restrict__ WcT, float* __restrict__ bc)
{
    __shared__ __align__(16) ushort As[64 * 128];   // 16 KB (swizzled)
    __shared__ __align__(16) ushort Bs[64 * 128];   // 16 KB (swizzled)
    const int bid = blockIdx.x;
    const int t = threadIdx.x;
    if (bid < 288) {
        const int m0 = (bid / 12) * 64, n0 = (bid % 12) * 64;
        const int lane = t & 63, w = t >> 6;
        const int lg = lane >> 4, lc = lane & 15;
        const int wr = (w >> 1) * 32, wc = (w & 1) * 32;
        f32x4 acc[2][2] = {};
        for (int kh = 0; kh < 2; ++kh) {
            if (kh) __syncthreads();      // WAR vs previous half's reads
            #pragma unroll
            for (int i = 0; i < 4; ++i) { // stage A,B (fp32->bf16), burst issue
                int v = t + 256 * i;
                int r = v >> 4, c8 = v & 15;
                const float* ap = features + (size_t)(m0 + r) * 256 + kh * 128 + c8 * 8;
                const float* bp = in_proj_w + (size_t)(n0 + r) * 256 + kh * 128 + c8 * 8;
                *(uint4*)&As[SWZ(r, c8 * 8)] = pack8(*(const float4*)ap, *(const float4*)(ap + 4));
                *(uint4*)&Bs[SWZ(r, c8 * 8)] = pack8(*(const float4*)bp, *(const float4*)(bp + 4));
            }
            __syncthreads();
            #pragma unroll
            for (int kk = 0; kk < 4; ++kk) {
                bf16x8 a0 = *(const bf16x8*)&As[SWZ(wr + lc,      kk * 32 + 8 * lg)];
                bf16x8 a1 = *(const bf16x8*)&As[SWZ(wr + 16 + lc, kk * 32 + 8 * lg)];
                bf16x8 b0 = *(const bf16x8*)&Bs[SWZ(wc + lc,      kk * 32 + 8 * lg)];
                bf16x8 b1 = *(const bf16x8*)&Bs[SWZ(wc + 16 + lc, kk * 32 + 8 * lg)];
                acc[0][0] = __builtin_amdgcn_mfma_f32_16x16x32_bf16(a0, b0, acc[0][0], 0, 0, 0);
                acc[0][1] = __builtin_amdgcn_mfma_f32_16x16x32_bf16(a0, b1, acc[0][1], 0, 0, 0);
                acc[1][0] = __builtin_amdgcn_mfma_f32_16x16x32_bf16(a1, b0, acc[1][0], 0, 0, 0);
                acc[1][1] = __builtin_amdgcn_mfma_f32_16x16x32_bf16(a1, b1, acc[1][1], 0, 0, 0);
            }
        }
        #pragma unroll
        for (int ia = 0; ia < 2; ++ia) {
            const int mrow0 = m0 + wr + 16 * ia;     // 16-aligned; one batch
            const int bb2 = mrow0 >= 768;
            const int seq0 = mrow0 - bb2 * 768;
            #pragma unroll
            for (int j = 0; j < 2; ++j) {
                const int ng = n0 + wc + 16 * j;     // wave-uniform group base
                const int n = ng + lc;
                const float bv = in_proj_b[n];
                if (ng < 512) {
                    const float sc = ng < 256 ? QSC : 1.0f;
                    #pragma unroll
                    for (int ii = 0; ii < 4; ++ii)
                        qkvb[(size_t)(mrow0 + 4 * lg + ii) * 768 + n] =
                            f2bf((acc[ia][j][ii] + bv) * sc);
                } else {
                    const int hh = (n - 512) >> 5, dd = (n - 512) & 31;
                    const int seqb = seq0 + 4 * lg;          // 4-aligned
                    const int pos = (seqb & ~31) + 8 * ((seqb >> 2) & 3) + 4 * ((seqb >> 4) & 1);
                    ushort* vp = vtp + (size_t)((bb2 * 8 + hh) * 32 + dd) * 768 + pos;
                    uint lo = pack2(acc[ia][j][0] + bv, acc[ia][j][1] + bv);
                    uint hi = pack2(acc[ia][j][2] + bv, acc[ia][j][3] + bv);
                    *(uint2*)vp = make_uint2(lo, hi);
                }
            }
        }
    } else if (bid < 352) {
        float (*Aw)[33] = (float(*)[33])As;    // overlay (different branch)
        float (*Bw)[33] = (float(*)[33])Bs;
        const int u2 = bid - 288;
        const int k0 = (u2 & 7) * 32, c0 = (u2 >> 3) * 32;
        const float* w1x = w1 + (c0 >= 128 ? 256 * 128 : 0);
        const int cc0 = c0 & 127;
        const int tx = t & 15, ty = t >> 4;
        float acc[2][2] = {};
        for (int j0 = 0; j0 < 256; j0 += 32) {
            __syncthreads();
            for (int v = t; v < 32 * 32; v += 256) {
                int r = v >> 5, c = v & 31;
                Aw[r][c] = out_w[(size_t)(j0 + r) * 256 + k0 + c];
                Bw[r][c] = w1x[(size_t)(j0 + r) * 128 + cc0 + c];
            }
            __syncthreads();
            #pragma unroll
            for (int jj = 0; jj < 32; ++jj) {
                float a0 = Aw[jj][ty * 2], a1 = Aw[jj][ty * 2 + 1];
                float b0 = Bw[jj][tx * 2], b1v = Bw[jj][tx * 2 + 1];
                acc[0][0] = fmaf(a0, b0, acc[0][0]);
                acc[0][1] = fmaf(a0, b1v, acc[0][1]);
                acc[1][0] = fmaf(a1, b0, acc[1][0]);
                acc[1][1] = fmaf(a1, b1v, acc[1][1]);
            }
        }
        #pragma unroll
        for (int i = 0; i < 2; ++i)
            #pragma unroll
            for (int j = 0; j < 2; ++j)
                WcT[(size_t)(c0 + tx * 2 + j) * 256 + (k0 + ty * 2 + i)] = f2bf(acc[i][j]);
    } else {
        const float* w1x = w1 + (t >= 128 ? 256 * 128 : 0);
        const int cc = t & 127;
        float a = 0.f;
        #pragma unroll 8
        for (int j = 0; j < 256; ++j)
            a = fmaf(out_b[j], w1x[(size_t)j * 128 + cc], a);
        bc[t] = a + (t < 128 ? b1[cc] : 0.f);
    }
}

// ---------------------------------------------------------------------------
// attn_kernel: grid (48, 16). Block = one 16-row q-tile of one (b,h);
// 4 waves split K (192 each). Swapped QK^T + no-max softmax (p=2^s) +
// slot-permuted V so P feeds PV directly. ALL 12 K-fragments preloaded
// before the loop (single latency exposure); V loads issued at iter top.
// ---------------------------------------------------------------------------
__global__ __launch_bounds__(256) void attn_kernel(
    const ushort* __restrict__ qkvb, const ushort* __restrict__ vtp,
    ushort* __restrict__ attnb)
{
    __shared__ float Ow[4][16][33];
    __shared__ float Lw[4][16];
    const int qt = blockIdx.x, bh = blockIdx.y, b = bh >> 3, h = bh & 7;
    const int m0 = qt * 16;
    const int t = threadIdx.x, lane = t & 63, w = t >> 6;
    const int lg = lane >> 4, lc = lane & 15;
    const ushort* qbase = qkvb + (size_t)(b * NL) * 768;
    const ushort* vbase = vtp + (size_t)((b * 8 + h) * 32) * 768;

    bf16x8 qa = *(const bf16x8*)(qbase + (size_t)(m0 + lc) * 768 + h * 32 + 8 * lg);

    bf16x8 kb[3][4];
    #pragma unroll
    for (int kt = 0; kt < 3; ++kt)
        #pragma unroll
        for (int t4 = 0; t4 < 4; ++t4)
            kb[kt][t4] = *(const bf16x8*)(qbase
                + (size_t)(w * 192 + kt * 64 + 16 * t4 + lc) * 768 + 256 + h * 32 + 8 * lg);

    f32x4 o0 = {}, o1 = {};
    float lsum = 0.f;

    #pragma unroll
    for (int kt = 0; kt < 3; ++kt) {
        const int k0 = w * 192 + kt * 64;
        bf16x8 v00 = *(const bf16x8*)(vbase + (size_t)lc * 768 + k0 + 8 * lg);
        bf16x8 v01 = *(const bf16x8*)(vbase + (size_t)lc * 768 + k0 + 32 + 8 * lg);
        bf16x8 v10 = *(const bf16x8*)(vbase + (size_t)(16 + lc) * 768 + k0 + 8 * lg);
        bf16x8 v11 = *(const bf16x8*)(vbase + (size_t)(16 + lc) * 768 + k0 + 32 + 8 * lg);
        f32x4 s[4];
        #pragma unroll
        for (int t4 = 0; t4 < 4; ++t4) {
            f32x4 z = {};
            s[t4] = __builtin_amdgcn_mfma_f32_16x16x32_bf16(kb[kt][t4], qa, z, 0, 0, 0);
        }
        uint pk[4][2];
        #pragma unroll
        for (int t4 = 0; t4 < 4; ++t4) {
            float p0 = fexp2(s[t4][0]);
            float p1 = fexp2(s[t4][1]);
            float p2 = fexp2(s[t4][2]);
            float p3 = fexp2(s[t4][3]);
            lsum += (p0 + p1) + (p2 + p3);
            pk[t4][0] = pack2(p0, p1);
            pk[t4][1] = pack2(p2, p3);
        }
        #pragma unroll
        for (int c = 0; c < 2; ++c) {
            uint4 au;
            au.x = pk[2 * c][0];     au.y = pk[2 * c][1];
            au.z = pk[2 * c + 1][0]; au.w = pk[2 * c + 1][1];
            bf16x8 pa = __builtin_bit_cast(bf16x8, au);
            bf16x8 vA = c == 0 ? v00 : v01;
            bf16x8 vB = c == 0 ? v10 : v11;
            o0 = __builtin_amdgcn_mfma_f32_16x16x32_bf16(pa, vA, o0, 0, 0, 0);
            o1 = __builtin_amdgcn_mfma_f32_16x16x32_bf16(pa, vB, o1, 0, 0, 0);
        }
    }
    lsum += __shfl_xor(lsum, 16);
    lsum += __shfl_xor(lsum, 32);
    #pragma unroll
    for (int i = 0; i < 4; ++i) {
        Ow[w][4 * lg + i][lc] = o0[i];
        Ow[w][4 * lg + i][16 + lc] = o1[i];
    }
    if (lg == 0) Lw[w][lc] = lsum;
    __syncthreads();
    {
        const int q = 4 * w + lg;
        float l = (Lw[0][q] + Lw[1][q]) + (Lw[2][q] + Lw[3][q]);
        float inv = 1.f / l;
        float a0 = (Ow[0][q][lc] + Ow[1][q][lc]) + (Ow[2][q][lc] + Ow[3][q][lc]);
        float a1 = (Ow[0][q][16 + lc] + Ow[1][q][16 + lc])
                 + (Ow[2][q][16 + lc] + Ow[3][q][16 + lc]);
        size_t orow = (size_t)(b * NL + m0 + q);
        attnb[orow * 256 + h * 32 + lc] = f2bf(a0 * inv);
        attnb[orow * 256 + h * 32 + 16 + lc] = f2bf(a1 * inv);
    }
}

// ---------------------------------------------------------------------------
// rowcol_kernel: per-wave 16x16 tile, K=256, loads force-hoisted. 384 blocks.
// ---------------------------------------------------------------------------
__global__ __launch_bounds__(256) void rowcol_kernel(
    const ushort* __restrict__ attnb, const ushort* __restrict__ WcT,
    const float* __restrict__ bc, ushort* __restrict__ rowcol)
{
    const int t = threadIdx.x, lane = t & 63, w = t >> 6;
    const int lg = lane >> 4, lc = lane & 15;
    const int u = blockIdx.x * 4 + w;          // [0,1536)
    const int m0 = (u >> 4) * 16, n0 = (u & 15) * 16;
    bf16x8 a[8], br[8];
    #pragma unroll
    for (int i = 0; i < 8; ++i) {
        a[i]  = *(const bf16x8*)(attnb + (size_t)(m0 + lc) * 256 + i * 32 + 8 * lg);
        br[i] = *(const bf16x8*)(WcT   + (size_t)(n0 + lc) * 256 + i * 32 + 8 * lg);
    }
    f32x4 acc = {};
    #pragma unroll
    for (int i = 0; i < 8; ++i)
        acc = __builtin_amdgcn_mfma_f32_16x16x32_bf16(a[i], br[i], acc, 0, 0, 0);
    const int n = n0 + lc;
    const float bv = bc[n];
    #pragma unroll
    for (int ii = 0; ii < 4; ++ii)
        ((_Float16*)rowcol)[(size_t)(m0 + 4 * lg + ii) * 256 + n] = (_Float16)(acc[ii] + bv);
}

// ---------------------------------------------------------------------------
// pairwise_kernel: grid (12, 24, 2); block tile 32(i) x 64(j), 4 waves 2x2,
// per-lane 2x4 outputs; fp16 addrelu+dot2; broadcast-friendly LDS.
// ---------------------------------------------------------------------------
__global__ __launch_bounds__(256) void pairwise_kernel(
    const ushort* __restrict__ rowcol, const float* __restrict__ w2,
    const float* __restrict__ b2, float* __restrict__ out)
{
    __shared__ __align__(16) ushort rs[32 * 136];
    __shared__ __align__(16) ushort cs[64 * 136];
    __shared__ uint w2u[64];
    const int b = blockIdx.z, i0 = blockIdx.y * 32, j0 = blockIdx.x * 64;
    const int t = threadIdx.x;
    #pragma unroll
    for (int v = t; v < 512; v += 256) {
        int r = v >> 4, q = v & 15;
        *(uint4*)&rs[r * 136 + q * 8] =
            *(const uint4*)(rowcol + (size_t)(b * NL + i0 + r) * 256 + q * 8);
    }
    #pragma unroll
    for (int v = t; v < 1024; v += 256) {
        int r = v >> 4, q = v & 15;
        *(uint4*)&cs[r * 136 + q * 8] =
            *(const uint4*)(rowcol + (size_t)(b * NL + j0 + r) * 256 + 128 + q * 8);
    }
    if (t < 64) {
        float2 wv = *(const float2*)&w2[2 * t];
        h2v hw = {(_Float16)wv.x, (_Float16)wv.y};
        w2u[t] = __builtin_bit_cast(uint, hw);
    }
    __syncthreads();
    const int lane = t & 63, w = t >> 6;
    const int rg = lane >> 3, cg = lane & 7;
    const int wy = w >> 1, wx = w & 1;
    float acc[2][4] = {};
    for (int c8 = 0; c8 < 128; c8 += 8) {
        uint wu[4];
        *(uint4*)wu = *(const uint4*)&w2u[c8 >> 1];
        uint ru[2][4], cu[4][4];
        #pragma unroll
        for (int i = 0; i < 2; ++i)
            *(uint4*)ru[i] = *(const uint4*)&rs[(16 * wy + rg + 8 * i) * 136 + c8];
        #pragma unroll
        for (int j = 0; j < 4; ++j)
            *(uint4*)cu[j] = *(const uint4*)&cs[(32 * wx + cg + 8 * j) * 136 + c8];
        #pragma unroll
        for (int i = 0; i < 2; ++i)
            #pragma unroll
            for (int j = 0; j < 4; ++j) {
                float a = acc[i][j];
                #pragma unroll
                for (int p = 0; p < 4; ++p)
                    a = fdot2u(addrelu2(ru[i][p], cu[j][p]), wu[p], a);
                acc[i][j] = a;
            }
    }
    const float bb = b2[0];
    #pragma unroll
    for (int i = 0; i < 2; ++i)
        #pragma unroll
        for (int j = 0; j < 4; ++j)
            out[(size_t)(b * NL + i0 + 16 * wy + rg + 8 * i) * NL
                + j0 + 32 * wx + cg + 8 * j] = acc[i][j] + bb;
}

// ---------------------------------------------------------------------------
extern "C" void kernel_launch(void* const* d_in, const int* in_sizes, int n_in,
                              void* d_out, int out_size, void* d_ws, size_t ws_size,
                              hipStream_t stream)
{
    const float* features  = (const float*)d_in[0];  // [2,768,256]
    const float* in_proj_w = (const float*)d_in[1];  // [768,256]
    const float* in_proj_b = (const float*)d_in[2];  // [768]
    const float* out_w     = (const float*)d_in[3];  // [256,256]
    const float* out_b     = (const float*)d_in[4];  // [256]
    const float* w1        = (const float*)d_in[5];  // [512,128]
    const float* b1        = (const float*)d_in[6];  // [128]
    const float* w2        = (const float*)d_in[7];  // [128,1]
    const float* b2        = (const float*)d_in[8];  // [1]
    float* out = (float*)d_out;                      // [2,768,768]

    ushort* qkvb   = (ushort*)d_ws;                  // [1536,768] bf16 (Q scaled, K)
    ushort* vtp    = qkvb + 1179648;                 // [512,768]  bf16 V^T, slot-permuted
    ushort* attnb  = vtp + 393216;                   // [1536,256] bf16
    ushort* WcT    = attnb + 393216;                 // [256,256]  bf16
    float*  bc     = (float*)(WcT + 65536);          // [256] fp32
    ushort* rowcol = (ushort*)(bc + 256);            // [1536,256] fp16

    // 1. qkv projection (LDS-staged 64x64 tiles) + combined pairwise weights
    front_kernel<<<dim3(353), 256, 0, stream>>>(
        features, in_proj_w, in_proj_b, out_w, out_b, w1, b1, qkvb, vtp, WcT, bc);

    // 2. split-K flash attention, K-frags preloaded (768 blocks)
    attn_kernel<<<dim3(48, 16), 256, 0, stream>>>(qkvb, vtp, attnb);

    // 3. rowcol = attn @ Wc + bc -> fp16 (per-wave 16x16, 384 blocks)
    rowcol_kernel<<<dim3(384), 256, 0, stream>>>(attnb, WcT, bc, rowcol);

    // 4. pairwise contact MLP (576 blocks)
    pairwise_kernel<<<dim3(12, 24, 2), 256, 0, stream>>>(rowcol, w2, b2, out);
}

// Round 11
// 49.196 us; speedup vs baseline: 11.0074x; 1.0362x over previous
//
#include <hip/hip_runtime.h>
#include <math.h>

// Problem constants: B=2, L=768, H=256, NH=8, HD=32
#define NL 768

typedef __attribute__((ext_vector_type(8))) short bf16x8;  // 8 bf16 = 4 VGPR
typedef __attribute__((ext_vector_type(4))) float f32x4;
typedef _Float16 h2v __attribute__((ext_vector_type(2)));

static __device__ __forceinline__ ushort f2bf(float f) {
    uint u = __float_as_uint(f);
    u += 0x7fffu + ((u >> 16) & 1u);           // round-to-nearest-even
    return (ushort)(u >> 16);
}
static __device__ __forceinline__ uint pack2(float a, float b) {
    return (uint)f2bf(a) | ((uint)f2bf(b) << 16);
}
static __device__ __forceinline__ uint4 pack8(float4 a, float4 b) {
    uint4 r;
    r.x = pack2(a.x, a.y); r.y = pack2(a.z, a.w);
    r.z = pack2(b.x, b.y); r.w = pack2(b.z, b.w);
    return r;
}
// packed fp16: relu(a+b) via v_pk_add_f16 + v_pk_max_f16
static __device__ __forceinline__ uint addrelu2(uint a, uint b) {
    h2v s = __builtin_bit_cast(h2v, a) + __builtin_bit_cast(h2v, b);
    h2v z = {(_Float16)0.f, (_Float16)0.f};
    s = __builtin_elementwise_max(s, z);
    return __builtin_bit_cast(uint, s);
}
// fp32 += dot2(fp16x2, fp16x2) via v_dot2_f32_f16
static __device__ __forceinline__ float fdot2u(uint a, uint b, float c) {
#if __has_builtin(__builtin_amdgcn_fdot2)
    return __builtin_amdgcn_fdot2(__builtin_bit_cast(h2v, a),
                                  __builtin_bit_cast(h2v, b), c, false);
#else
    h2v x = __builtin_bit_cast(h2v, a), y = __builtin_bit_cast(h2v, b);
    return fmaf((float)x[1], (float)y[1], fmaf((float)x[0], (float)y[0], c));
#endif
}
static __device__ __forceinline__ float fexp2(float x) {
#if __has_builtin(__builtin_amdgcn_exp2f)
    return __builtin_amdgcn_exp2f(x);
#else
    return exp2f(x);
#endif
}

// 1/sqrt(32) * log2(e): folded into Q at write time so attn uses exp2 directly
#define QSC 0.25503487f

// XOR-swizzled element index for bf16 LDS tile with 128-element rows (256 B)
#define SWZ(r, ce) (((((r) * 256 + (ce) * 2) ^ (((r) & 7) << 4))) >> 1)

// ---------------------------------------------------------------------------
// front_kernel, grid 353 x 512 threads.
//  blocks [0,288):   LDS-staged bf16 GEMM, 64x64 C-tile, 8 waves of 16x32.
//    Output: n<256 -> Q (pre-scaled QSC) -> qkvb; n<512 -> K -> qkvb;
//            n>=512 -> V -> vtp[(b,h,d)][seq] slot-permuted (see R7).
//  blocks [288,352): combine_w 32x32 (first 256 threads; uniform barriers)
//  block 352:        combine_bias (first 256 threads)
// ---------------------------------------------------------------------------
__global__ __launch_bounds__(512) void front_kernel(
    const float* __restrict__ features, const float* __restrict__ in_proj_w,
    const float* __restrict__ in_proj_b, const float* __restrict__ out_w,
    const float* __restrict__ out_b, const float* __restrict__ w1,
    const float* __restrict__ b1,
    ushort* __restrict__ qkvb, ushort* __restrict__ vtp,
    ushort* __restrict__ WcT, float* __restrict__ bc)
{
    __shared__ __align__(16) ushort As[64 * 128];   // 16 KB (swizzled)
    __shared__ __align__(16) ushort Bs[64 * 128];   // 16 KB (swizzled)
    const int bid = blockIdx.x;
    const int t = threadIdx.x;
    if (bid < 288) {
        const int m0 = (bid / 12) * 64, n0 = (bid % 12) * 64;
        const int lane = t & 63, w = t >> 6;            // w 0..7
        const int lg = lane >> 4, lc = lane & 15;
        const int wr = (w >> 1) * 16, wc = (w & 1) * 32;
        f32x4 acc[2] = {};
        for (int kh = 0; kh < 2; ++kh) {
            if (kh) __syncthreads();      // WAR vs previous half's reads
            #pragma unroll
            for (int i = 0; i < 4; ++i) { // 2048 uint4 units: A then B
                int v = t + 512 * i;
                if (v < 1024) {
                    int r = v >> 4, c8 = v & 15;
                    const float* ap = features + (size_t)(m0 + r) * 256 + kh * 128 + c8 * 8;
                    *(uint4*)&As[SWZ(r, c8 * 8)] =
                        pack8(*(const float4*)ap, *(const float4*)(ap + 4));
                } else {
                    int v2 = v - 1024;
                    int r = v2 >> 4, c8 = v2 & 15;
                    const float* bp = in_proj_w + (size_t)(n0 + r) * 256 + kh * 128 + c8 * 8;
                    *(uint4*)&Bs[SWZ(r, c8 * 8)] =
                        pack8(*(const float4*)bp, *(const float4*)(bp + 4));
                }
            }
            __syncthreads();
            #pragma unroll
            for (int kk = 0; kk < 4; ++kk) {
                bf16x8 a0 = *(const bf16x8*)&As[SWZ(wr + lc,      kk * 32 + 8 * lg)];
                bf16x8 b0 = *(const bf16x8*)&Bs[SWZ(wc + lc,      kk * 32 + 8 * lg)];
                bf16x8 b1 = *(const bf16x8*)&Bs[SWZ(wc + 16 + lc, kk * 32 + 8 * lg)];
                acc[0] = __builtin_amdgcn_mfma_f32_16x16x32_bf16(a0, b0, acc[0], 0, 0, 0);
                acc[1] = __builtin_amdgcn_mfma_f32_16x16x32_bf16(a0, b1, acc[1], 0, 0, 0);
            }
        }
        const int mrow0 = m0 + wr;                   // 16-aligned; one batch
        const int bb2 = mrow0 >= 768;
        const int seq0 = mrow0 - bb2 * 768;
        #pragma unroll
        for (int j = 0; j < 2; ++j) {
            const int ng = n0 + wc + 16 * j;         // wave-uniform group base
            const int n = ng + lc;
            const float bv = in_proj_b[n];
            if (ng < 512) {
                const float sc = ng < 256 ? QSC : 1.0f;
                #pragma unroll
                for (int ii = 0; ii < 4; ++ii)
                    qkvb[(size_t)(mrow0 + 4 * lg + ii) * 768 + n] =
                        f2bf((acc[j][ii] + bv) * sc);
            } else {
                const int hh = (n - 512) >> 5, dd = (n - 512) & 31;
                const int seqb = seq0 + 4 * lg;      // 4-aligned
                const int pos = (seqb & ~31) + 8 * ((seqb >> 2) & 3) + 4 * ((seqb >> 4) & 1);
                ushort* vp = vtp + (size_t)((bb2 * 8 + hh) * 32 + dd) * 768 + pos;
                uint lo = pack2(acc[j][0] + bv, acc[j][1] + bv);
                uint hi = pack2(acc[j][2] + bv, acc[j][3] + bv);
                *(uint2*)vp = make_uint2(lo, hi);
            }
        }
    } else if (bid < 352) {
        float (*Aw)[33] = (float(*)[33])As;    // overlay (different branch)
        float (*Bw)[33] = (float(*)[33])Bs;
        const int u2 = bid - 288;
        const int k0 = (u2 & 7) * 32, c0 = (u2 >> 3) * 32;
        const float* w1x = w1 + (c0 >= 128 ? 256 * 128 : 0);
        const int cc0 = c0 & 127;
        const int tx = t & 15, ty = (t & 255) >> 4;
        float acc[2][2] = {};
        for (int j0 = 0; j0 < 256; j0 += 32) {
            __syncthreads();
            if (t < 256) {
                for (int v = t; v < 32 * 32; v += 256) {
                    int r = v >> 5, c = v & 31;
                    Aw[r][c] = out_w[(size_t)(j0 + r) * 256 + k0 + c];
                    Bw[r][c] = w1x[(size_t)(j0 + r) * 128 + cc0 + c];
                }
            }
            __syncthreads();
            if (t < 256) {
                #pragma unroll
                for (int jj = 0; jj < 32; ++jj) {
                    float a0 = Aw[jj][ty * 2], a1 = Aw[jj][ty * 2 + 1];
                    float b0 = Bw[jj][tx * 2], b1v = Bw[jj][tx * 2 + 1];
                    acc[0][0] = fmaf(a0, b0, acc[0][0]);
                    acc[0][1] = fmaf(a0, b1v, acc[0][1]);
                    acc[1][0] = fmaf(a1, b0, acc[1][0]);
                    acc[1][1] = fmaf(a1, b1v, acc[1][1]);
                }
            }
        }
        if (t < 256) {
            #pragma unroll
            for (int i = 0; i < 2; ++i)
                #pragma unroll
                for (int j = 0; j < 2; ++j)
                    WcT[(size_t)(c0 + tx * 2 + j) * 256 + (k0 + ty * 2 + i)] = f2bf(acc[i][j]);
        }
    } else if (t < 256) {
        const float* w1x = w1 + (t >= 128 ? 256 * 128 : 0);
        const int cc = t & 127;
        float a = 0.f;
        #pragma unroll 8
        for (int j = 0; j < 256; ++j)
            a = fmaf(out_b[j], w1x[(size_t)j * 128 + cc], a);
        bc[t] = a + (t < 128 ? b1[cc] : 0.f);
    }
}

// ---------------------------------------------------------------------------
// attn_kernel: grid (24, 16) x 512 threads. Block = 32 q-rows of one (b,h);
// 8 waves split K (96 rows each). Swapped QK^T + no-max softmax (p=2^s) +
// slot-permuted V so P feeds PV directly. K frags preloaded. One barrier.
// ---------------------------------------------------------------------------
__global__ __launch_bounds__(512) void attn_kernel(
    const ushort* __restrict__ qkvb, const ushort* __restrict__ vtp,
    ushort* __restrict__ attnb)
{
    __shared__ float Ow[8][32][33];
    __shared__ float Lw[8][32];
    const int qt = blockIdx.x, bh = blockIdx.y, b = bh >> 3, h = bh & 7;
    const int m0 = qt * 32;
    const int t = threadIdx.x, lane = t & 63, w = t >> 6;   // w 0..7
    const int lg = lane >> 4, lc = lane & 15;
    const ushort* qbase = qkvb + (size_t)(b * NL) * 768;
    const ushort* vbase = vtp + (size_t)((b * 8 + h) * 32) * 768;

    // Q fragments (B-operand): qf selects q-rows m0+16*qf+lc
    bf16x8 qa[2];
    #pragma unroll
    for (int qf = 0; qf < 2; ++qf)
        qa[qf] = *(const bf16x8*)(qbase + (size_t)(m0 + 16 * qf + lc) * 768 + h * 32 + 8 * lg);

    // K fragments (A-operand): rows w*96 + 16*t4 + lc, t4 < 6
    bf16x8 kb[6];
    #pragma unroll
    for (int t4 = 0; t4 < 6; ++t4)
        kb[t4] = *(const bf16x8*)(qbase
            + (size_t)(w * 96 + 16 * t4 + lc) * 768 + 256 + h * 32 + 8 * lg);

    f32x4 o[2][2] = {};
    float lsum[2] = {0.f, 0.f};

    #pragma unroll
    for (int kc = 0; kc < 3; ++kc) {            // 32 k-rows per iteration
        const int k0 = w * 96 + kc * 32;
        bf16x8 v0 = *(const bf16x8*)(vbase + (size_t)lc * 768 + k0 + 8 * lg);
        bf16x8 v1 = *(const bf16x8*)(vbase + (size_t)(16 + lc) * 768 + k0 + 8 * lg);
        #pragma unroll
        for (int qf = 0; qf < 2; ++qf) {
            f32x4 z = {};
            f32x4 s0 = __builtin_amdgcn_mfma_f32_16x16x32_bf16(kb[2 * kc],     qa[qf], z, 0, 0, 0);
            f32x4 s1 = __builtin_amdgcn_mfma_f32_16x16x32_bf16(kb[2 * kc + 1], qa[qf], z, 0, 0, 0);
            float p0 = fexp2(s0[0]), p1 = fexp2(s0[1]), p2 = fexp2(s0[2]), p3 = fexp2(s0[3]);
            float p4 = fexp2(s1[0]), p5 = fexp2(s1[1]), p6 = fexp2(s1[2]), p7 = fexp2(s1[3]);
            lsum[qf] += ((p0 + p1) + (p2 + p3)) + ((p4 + p5) + (p6 + p7));
            uint4 au;
            au.x = pack2(p0, p1); au.y = pack2(p2, p3);
            au.z = pack2(p4, p5); au.w = pack2(p6, p7);
            bf16x8 pa = __builtin_bit_cast(bf16x8, au);
            o[qf][0] = __builtin_amdgcn_mfma_f32_16x16x32_bf16(pa, v0, o[qf][0], 0, 0, 0);
            o[qf][1] = __builtin_amdgcn_mfma_f32_16x16x32_bf16(pa, v1, o[qf][1], 0, 0, 0);
        }
    }
    // publish partials
    #pragma unroll
    for (int qf = 0; qf < 2; ++qf) {
        float ls = lsum[qf];
        ls += __shfl_xor(ls, 16);
        ls += __shfl_xor(ls, 32);
        #pragma unroll
        for (int i = 0; i < 4; ++i) {
            Ow[w][16 * qf + 4 * lg + i][lc]      = o[qf][0][i];
            Ow[w][16 * qf + 4 * lg + i][16 + lc] = o[qf][1][i];
        }
        if (lg == 0) Lw[w][16 * qf + lc] = ls;
    }
    __syncthreads();
    // merge: thread t -> q = t>>4 (0..31), d = t&15 (and d+16)
    {
        const int q = t >> 4, d = t & 15;
        float l = 0.f, a0 = 0.f, a1 = 0.f;
        #pragma unroll
        for (int p = 0; p < 8; ++p) {
            l  += Lw[p][q];
            a0 += Ow[p][q][d];
            a1 += Ow[p][q][16 + d];
        }
        float inv = 1.f / l;
        size_t orow = (size_t)(b * NL + m0 + q);
        attnb[orow * 256 + h * 32 + d]      = f2bf(a0 * inv);
        attnb[orow * 256 + h * 32 + 16 + d] = f2bf(a1 * inv);
    }
}

// ---------------------------------------------------------------------------
// rowcol_kernel: per-wave 16x16 tile, K=256, loads force-hoisted. 384 blocks.
// ---------------------------------------------------------------------------
__global__ __launch_bounds__(256) void rowcol_kernel(
    const ushort* __restrict__ attnb, const ushort* __restrict__ WcT,
    const float* __restrict__ bc, ushort* __restrict__ rowcol)
{
    const int t = threadIdx.x, lane = t & 63, w = t >> 6;
    const int lg = lane >> 4, lc = lane & 15;
    const int u = blockIdx.x * 4 + w;          // [0,1536)
    const int m0 = (u >> 4) * 16, n0 = (u & 15) * 16;
    bf16x8 a[8], br[8];
    #pragma unroll
    for (int i = 0; i < 8; ++i) {
        a[i]  = *(const bf16x8*)(attnb + (size_t)(m0 + lc) * 256 + i * 32 + 8 * lg);
        br[i] = *(const bf16x8*)(WcT   + (size_t)(n0 + lc) * 256 + i * 32 + 8 * lg);
    }
    f32x4 acc = {};
    #pragma unroll
    for (int i = 0; i < 8; ++i)
        acc = __builtin_amdgcn_mfma_f32_16x16x32_bf16(a[i], br[i], acc, 0, 0, 0);
    const int n = n0 + lc;
    const float bv = bc[n];
    #pragma unroll
    for (int ii = 0; ii < 4; ++ii)
        ((_Float16*)rowcol)[(size_t)(m0 + 4 * lg + ii) * 256 + n] = (_Float16)(acc[ii] + bv);
}

// ---------------------------------------------------------------------------
// pairwise_kernel: grid (12, 24, 2); block tile 32(i) x 64(j), 4 waves 2x2,
// per-lane 2x4 outputs; fp16 addrelu+dot2; broadcast-friendly LDS.
// ---------------------------------------------------------------------------
__global__ __launch_bounds__(256) void pairwise_kernel(
    const ushort* __restrict__ rowcol, const float* __restrict__ w2,
    const float* __restrict__ b2, float* __restrict__ out)
{
    __shared__ __align__(16) ushort rs[32 * 136];
    __shared__ __align__(16) ushort cs[64 * 136];
    __shared__ uint w2u[64];
    const int b = blockIdx.z, i0 = blockIdx.y * 32, j0 = blockIdx.x * 64;
    const int t = threadIdx.x;
    #pragma unroll
    for (int v = t; v < 512; v += 256) {
        int r = v >> 4, q = v & 15;
        *(uint4*)&rs[r * 136 + q * 8] =
            *(const uint4*)(rowcol + (size_t)(b * NL + i0 + r) * 256 + q * 8);
    }
    #pragma unroll
    for (int v = t; v < 1024; v += 256) {
        int r = v >> 4, q = v & 15;
        *(uint4*)&cs[r * 136 + q * 8] =
            *(const uint4*)(rowcol + (size_t)(b * NL + j0 + r) * 256 + 128 + q * 8);
    }
    if (t < 64) {
        float2 wv = *(const float2*)&w2[2 * t];
        h2v hw = {(_Float16)wv.x, (_Float16)wv.y};
        w2u[t] = __builtin_bit_cast(uint, hw);
    }
    __syncthreads();
    const int lane = t & 63, w = t >> 6;
    const int rg = lane >> 3, cg = lane & 7;
    const int wy = w >> 1, wx = w & 1;
    float acc[2][4] = {};
    for (int c8 = 0; c8 < 128; c8 += 8) {
        uint wu[4];
        *(uint4*)wu = *(const uint4*)&w2u[c8 >> 1];
        uint ru[2][4], cu[4][4];
        #pragma unroll
        for (int i = 0; i < 2; ++i)
            *(uint4*)ru[i] = *(const uint4*)&rs[(16 * wy + rg + 8 * i) * 136 + c8];
        #pragma unroll
        for (int j = 0; j < 4; ++j)
            *(uint4*)cu[j] = *(const uint4*)&cs[(32 * wx + cg + 8 * j) * 136 + c8];
        #pragma unroll
        for (int i = 0; i < 2; ++i)
            #pragma unroll
            for (int j = 0; j < 4; ++j) {
                float a = acc[i][j];
                #pragma unroll
                for (int p = 0; p < 4; ++p)
                    a = fdot2u(addrelu2(ru[i][p], cu[j][p]), wu[p], a);
                acc[i][j] = a;
            }
    }
    const float bb = b2[0];
    #pragma unroll
    for (int i = 0; i < 2; ++i)
        #pragma unroll
        for (int j = 0; j < 4; ++j)
            out[(size_t)(b * NL + i0 + 16 * wy + rg + 8 * i) * NL
                + j0 + 32 * wx + cg + 8 * j] = acc[i][j] + bb;
}

// ---------------------------------------------------------------------------
extern "C" void kernel_launch(void* const* d_in, const int* in_sizes, int n_in,
                              void* d_out, int out_size, void* d_ws, size_t ws_size,
                              hipStream_t stream)
{
    const float* features  = (const float*)d_in[0];  // [2,768,256]
    const float* in_proj_w = (const float*)d_in[1];  // [768,256]
    const float* in_proj_b = (const float*)d_in[2];  // [768]
    const float* out_w     = (const float*)d_in[3];  // [256,256]
    const float* out_b     = (const float*)d_in[4];  // [256]
    const float* w1        = (const float*)d_in[5];  // [512,128]
    const float* b1        = (const float*)d_in[6];  // [128]
    const float* w2        = (const float*)d_in[7];  // [128,1]
    const float* b2        = (const float*)d_in[8];  // [1]
    float* out = (float*)d_out;                      // [2,768,768]

    ushort* qkvb   = (ushort*)d_ws;                  // [1536,768] bf16 (Q scaled, K)
    ushort* vtp    = qkvb + 1179648;                 // [512,768]  bf16 V^T, slot-permuted
    ushort* attnb  = vtp + 393216;                   // [1536,256] bf16
    ushort* WcT    = attnb + 393216;                 // [256,256]  bf16
    float*  bc     = (float*)(WcT + 65536);          // [256] fp32
    ushort* rowcol = (ushort*)(bc + 256);            // [1536,256] fp16

    // 1. qkv projection (512-thread LDS-staged tiles) + combined weights
    front_kernel<<<dim3(353), 512, 0, stream>>>(
        features, in_proj_w, in_proj_b, out_w, out_b, w1, b1, qkvb, vtp, WcT, bc);

    // 2. flash attention: QBLK=32, 8-way split-K (384 blocks x 512 thr)
    attn_kernel<<<dim3(24, 16), 512, 0, stream>>>(qkvb, vtp, attnb);

    // 3. rowcol = attn @ Wc + bc -> fp16 (per-wave 16x16, 384 blocks)
    rowcol_kernel<<<dim3(384), 256, 0, stream>>>(attnb, WcT, bc, rowcol);

    // 4. pairwise contact MLP (576 blocks)
    pairwise_kernel<<<dim3(12, 24, 2), 256, 0, stream>>>(rowcol, w2, b2, out);
}

// Round 12
// 43.990 us; speedup vs baseline: 12.3100x; 1.1183x over previous
//
#include <hip/hip_runtime.h>
#include <math.h>

// Problem constants: B=2, L=768, H=256, NH=8, HD=32
#define NL 768

typedef __attribute__((ext_vector_type(8))) short bf16x8;  // 8 bf16 = 4 VGPR
typedef __attribute__((ext_vector_type(4))) float f32x4;
typedef _Float16 h2v __attribute__((ext_vector_type(2)));

static __device__ __forceinline__ ushort f2bf(float f) {
    uint u = __float_as_uint(f);
    u += 0x7fffu + ((u >> 16) & 1u);           // round-to-nearest-even
    return (ushort)(u >> 16);
}
static __device__ __forceinline__ uint pack2(float a, float b) {
    return (uint)f2bf(a) | ((uint)f2bf(b) << 16);
}
static __device__ __forceinline__ uint4 pack8(float4 a, float4 b) {
    uint4 r;
    r.x = pack2(a.x, a.y); r.y = pack2(a.z, a.w);
    r.z = pack2(b.x, b.y); r.w = pack2(b.z, b.w);
    return r;
}
// packed fp16: relu(a+b) via v_pk_add_f16 + v_pk_max_f16
static __device__ __forceinline__ uint addrelu2(uint a, uint b) {
    h2v s = __builtin_bit_cast(h2v, a) + __builtin_bit_cast(h2v, b);
    h2v z = {(_Float16)0.f, (_Float16)0.f};
    s = __builtin_elementwise_max(s, z);
    return __builtin_bit_cast(uint, s);
}
// fp32 += dot2(fp16x2, fp16x2) via v_dot2_f32_f16
static __device__ __forceinline__ float fdot2u(uint a, uint b, float c) {
#if __has_builtin(__builtin_amdgcn_fdot2)
    return __builtin_amdgcn_fdot2(__builtin_bit_cast(h2v, a),
                                  __builtin_bit_cast(h2v, b), c, false);
#else
    h2v x = __builtin_bit_cast(h2v, a), y = __builtin_bit_cast(h2v, b);
    return fmaf((float)x[1], (float)y[1], fmaf((float)x[0], (float)y[0], c));
#endif
}
static __device__ __forceinline__ float fexp2(float x) {
#if __has_builtin(__builtin_amdgcn_exp2f)
    return __builtin_amdgcn_exp2f(x);
#else
    return exp2f(x);
#endif
}

// 1/sqrt(32) * log2(e): folded into Q at write time so attn uses exp2 directly
#define QSC 0.25503487f

// XOR-swizzled element index for bf16 LDS tile with 128-element rows (256 B)
#define SWZ(r, ce) (((((r) * 256 + (ce) * 2) ^ (((r) & 7) << 4))) >> 1)

// ===========================================================================
// Fragment-major layouts (u16 elements; "lane" = (lg<<4)|lc, frag = 512 u16):
//  QF[(b*8+h)*48 + seq/16][lane*8+e]  : Q[seq][d], lane=((d/8)<<4)|(seq%16)
//  KF[(b*8+h)*48 + seq/16][...]       : same for K
//  VF[((b*8+h)*24 + seq/32)*2 + d/16][lane*8+e] : V^T, slot-permuted in seq
//  AF[(grow/16)*8 + h][...]           : attn out [1536,256], frag cols h*32+
//  BF[(n/16)*8 + k/32][...]           : WcT [256,256]
// Every consumer load = *(bf16x8*)(F + frag*512 + lane*8)  -> coalesced 1KB.
// ===========================================================================

// ---------------------------------------------------------------------------
// front_kernel, grid 353 x 512 threads.
//  blocks [0,288):   LDS-staged bf16 GEMM, 64x64 C-tile, 8 waves of 16x32.
//    Epilogue scatters into QF/KF/VF fragment-major layouts.
//  blocks [288,352): combine_w 32x32 -> BF.   block 352: combine_bias -> bc.
// ---------------------------------------------------------------------------
__global__ __launch_bounds__(512) void front_kernel(
    const float* __restrict__ features, const float* __restrict__ in_proj_w,
    const float* __restrict__ in_proj_b, const float* __restrict__ out_w,
    const float* __restrict__ out_b, const float* __restrict__ w1,
    const float* __restrict__ b1,
    ushort* __restrict__ QF, ushort* __restrict__ KF, ushort* __restrict__ VF,
    ushort* __restrict__ BF, float* __restrict__ bc)
{
    __shared__ __align__(16) ushort As[64 * 128];   // 16 KB (swizzled)
    __shared__ __align__(16) ushort Bs[64 * 128];   // 16 KB (swizzled)
    const int bid = blockIdx.x;
    const int t = threadIdx.x;
    if (bid < 288) {
        const int m0 = (bid / 12) * 64, n0 = (bid % 12) * 64;
        const int lane = t & 63, w = t >> 6;            // w 0..7
        const int lg = lane >> 4, lc = lane & 15;
        const int wr = (w >> 1) * 16, wc = (w & 1) * 32;
        f32x4 acc[2] = {};
        for (int kh = 0; kh < 2; ++kh) {
            if (kh) __syncthreads();      // WAR vs previous half's reads
            #pragma unroll
            for (int i = 0; i < 4; ++i) { // 2048 uint4 units: A then B
                int v = t + 512 * i;
                if (v < 1024) {
                    int r = v >> 4, c8 = v & 15;
                    const float* ap = features + (size_t)(m0 + r) * 256 + kh * 128 + c8 * 8;
                    *(uint4*)&As[SWZ(r, c8 * 8)] =
                        pack8(*(const float4*)ap, *(const float4*)(ap + 4));
                } else {
                    int v2 = v - 1024;
                    int r = v2 >> 4, c8 = v2 & 15;
                    const float* bp = in_proj_w + (size_t)(n0 + r) * 256 + kh * 128 + c8 * 8;
                    *(uint4*)&Bs[SWZ(r, c8 * 8)] =
                        pack8(*(const float4*)bp, *(const float4*)(bp + 4));
                }
            }
            __syncthreads();
            #pragma unroll
            for (int kk = 0; kk < 4; ++kk) {
                bf16x8 a0 = *(const bf16x8*)&As[SWZ(wr + lc,      kk * 32 + 8 * lg)];
                bf16x8 b0 = *(const bf16x8*)&Bs[SWZ(wc + lc,      kk * 32 + 8 * lg)];
                bf16x8 b1 = *(const bf16x8*)&Bs[SWZ(wc + 16 + lc, kk * 32 + 8 * lg)];
                acc[0] = __builtin_amdgcn_mfma_f32_16x16x32_bf16(a0, b0, acc[0], 0, 0, 0);
                acc[1] = __builtin_amdgcn_mfma_f32_16x16x32_bf16(a0, b1, acc[1], 0, 0, 0);
            }
        }
        const int mrow0 = m0 + wr;                   // 16-aligned; one batch
        const int bb2 = mrow0 >= 768;
        const int seq0 = mrow0 - bb2 * 768;
        const int mbL = seq0 >> 4;                   // 0..47
        #pragma unroll
        for (int j = 0; j < 2; ++j) {
            const int ng = n0 + wc + 16 * j;         // wave-uniform group base
            const int n = ng + lc;
            const float bv = in_proj_b[n];
            if (ng < 512) {                          // Q or K -> QF/KF
                const bool isQ = ng < 256;
                const int nh = (ng & 255) >> 5;      // head
                const int d0 = ng & 31;              // 0 or 16
                const float sc = isQ ? QSC : 1.0f;
                ushort* F = isQ ? QF : KF;
                size_t base = ((size_t)((bb2 * 8 + nh) * 48 + mbL)) * 512
                            + ((d0 >> 3) + (lc >> 3)) * 128 + (4 * lg) * 8 + (lc & 7);
                #pragma unroll
                for (int ii = 0; ii < 4; ++ii)
                    F[base + ii * 8] = f2bf((acc[j][ii] + bv) * sc);
            } else {                                 // V -> VF (slot-permuted)
                const int nh = (ng - 512) >> 5;
                const int c = ((ng - 512) & 31) >> 4;
                const int seqb = seq0 + 4 * lg;      // 4-aligned
                size_t vb2 = (((size_t)(bb2 * 8 + nh) * 24 + (seqb >> 5)) * 2 + c) * 512
                           + ((seqb >> 2) & 3) * 128 + lc * 8 + 4 * ((seqb >> 4) & 1);
                uint lo = pack2(acc[j][0] + bv, acc[j][1] + bv);
                uint hi = pack2(acc[j][2] + bv, acc[j][3] + bv);
                *(uint2*)&VF[vb2] = make_uint2(lo, hi);
            }
        }
    } else if (bid < 352) {
        float (*Aw)[33] = (float(*)[33])As;    // overlay (different branch)
        float (*Bw)[33] = (float(*)[33])Bs;
        const int u2 = bid - 288;
        const int k0 = (u2 & 7) * 32, c0 = (u2 >> 3) * 32;
        const float* w1x = w1 + (c0 >= 128 ? 256 * 128 : 0);
        const int cc0 = c0 & 127;
        const int tx = t & 15, ty = (t & 255) >> 4;
        float acc[2][2] = {};
        for (int j0 = 0; j0 < 256; j0 += 32) {
            __syncthreads();
            if (t < 256) {
                for (int v = t; v < 32 * 32; v += 256) {
                    int r = v >> 5, c = v & 31;
                    Aw[r][c] = out_w[(size_t)(j0 + r) * 256 + k0 + c];
                    Bw[r][c] = w1x[(size_t)(j0 + r) * 128 + cc0 + c];
                }
            }
            __syncthreads();
            if (t < 256) {
                #pragma unroll
                for (int jj = 0; jj < 32; ++jj) {
                    float a0 = Aw[jj][ty * 2], a1 = Aw[jj][ty * 2 + 1];
                    float b0 = Bw[jj][tx * 2], b1v = Bw[jj][tx * 2 + 1];
                    acc[0][0] = fmaf(a0, b0, acc[0][0]);
                    acc[0][1] = fmaf(a0, b1v, acc[0][1]);
                    acc[1][0] = fmaf(a1, b0, acc[1][0]);
                    acc[1][1] = fmaf(a1, b1v, acc[1][1]);
                }
            }
        }
        if (t < 256) {
            #pragma unroll
            for (int i = 0; i < 2; ++i)
                #pragma unroll
                for (int j = 0; j < 2; ++j) {
                    int n = c0 + tx * 2 + j, k = k0 + ty * 2 + i;   // WcT[n][k]
                    size_t bfb = ((size_t)(n >> 4) * 8 + (k >> 5)) * 512
                               + ((k & 31) >> 3) * 128 + (n & 15) * 8 + (k & 7);
                    BF[bfb] = f2bf(acc[i][j]);
                }
        }
    } else if (t < 256) {
        const float* w1x = w1 + (t >= 128 ? 256 * 128 : 0);
        const int cc = t & 127;
        float a = 0.f;
        #pragma unroll 8
        for (int j = 0; j < 256; ++j)
            a = fmaf(out_b[j], w1x[(size_t)j * 128 + cc], a);
        bc[t] = a + (t < 128 ? b1[cc] : 0.f);
    }
}

// ---------------------------------------------------------------------------
// attn_kernel: grid (24, 16) x 512 threads. Block = 32 q-rows of one (b,h);
// 8 waves split K (96 rows each). Swapped QK^T + no-max softmax (p=2^s) +
// slot-permuted V. ALL operand loads are coalesced fragment-major bursts.
// Output scattered into AF fragment-major for rowcol.
// ---------------------------------------------------------------------------
__global__ __launch_bounds__(512) void attn_kernel(
    const ushort* __restrict__ QF, const ushort* __restrict__ KF,
    const ushort* __restrict__ VF, ushort* __restrict__ AF)
{
    __shared__ float Ow[8][32][33];
    __shared__ float Lw[8][32];
    const int qt = blockIdx.x, bh = blockIdx.y, b = bh >> 3, h = bh & 7;
    const int m0 = qt * 32;
    const int t = threadIdx.x, lane = t & 63, w = t >> 6;   // w 0..7
    const int lg = lane >> 4, lc = lane & 15;

    const ushort* qfb = QF + ((size_t)bh * 48 + (m0 >> 4)) * 512 + lane * 8;
    const ushort* kfb = KF + ((size_t)bh * 48 + 6 * w) * 512 + lane * 8;
    const ushort* vfb = VF + ((size_t)bh * 24 + 3 * w) * 2 * 512 + lane * 8;

    bf16x8 qa[2];
    #pragma unroll
    for (int qf = 0; qf < 2; ++qf)
        qa[qf] = *(const bf16x8*)(qfb + qf * 512);

    bf16x8 kb[6];
    #pragma unroll
    for (int t4 = 0; t4 < 6; ++t4)
        kb[t4] = *(const bf16x8*)(kfb + t4 * 512);

    f32x4 o[2][2] = {};
    float lsum[2] = {0.f, 0.f};

    #pragma unroll
    for (int kc = 0; kc < 3; ++kc) {            // 32 k-rows per iteration
        bf16x8 v0 = *(const bf16x8*)(vfb + (kc * 2 + 0) * 512);
        bf16x8 v1 = *(const bf16x8*)(vfb + (kc * 2 + 1) * 512);
        #pragma unroll
        for (int qf = 0; qf < 2; ++qf) {
            f32x4 z = {};
            f32x4 s0 = __builtin_amdgcn_mfma_f32_16x16x32_bf16(kb[2 * kc],     qa[qf], z, 0, 0, 0);
            f32x4 s1 = __builtin_amdgcn_mfma_f32_16x16x32_bf16(kb[2 * kc + 1], qa[qf], z, 0, 0, 0);
            float p0 = fexp2(s0[0]), p1 = fexp2(s0[1]), p2 = fexp2(s0[2]), p3 = fexp2(s0[3]);
            float p4 = fexp2(s1[0]), p5 = fexp2(s1[1]), p6 = fexp2(s1[2]), p7 = fexp2(s1[3]);
            lsum[qf] += ((p0 + p1) + (p2 + p3)) + ((p4 + p5) + (p6 + p7));
            uint4 au;
            au.x = pack2(p0, p1); au.y = pack2(p2, p3);
            au.z = pack2(p4, p5); au.w = pack2(p6, p7);
            bf16x8 pa = __builtin_bit_cast(bf16x8, au);
            o[qf][0] = __builtin_amdgcn_mfma_f32_16x16x32_bf16(pa, v0, o[qf][0], 0, 0, 0);
            o[qf][1] = __builtin_amdgcn_mfma_f32_16x16x32_bf16(pa, v1, o[qf][1], 0, 0, 0);
        }
    }
    // publish partials
    #pragma unroll
    for (int qf = 0; qf < 2; ++qf) {
        float ls = lsum[qf];
        ls += __shfl_xor(ls, 16);
        ls += __shfl_xor(ls, 32);
        #pragma unroll
        for (int i = 0; i < 4; ++i) {
            Ow[w][16 * qf + 4 * lg + i][lc]      = o[qf][0][i];
            Ow[w][16 * qf + 4 * lg + i][16 + lc] = o[qf][1][i];
        }
        if (lg == 0) Lw[w][16 * qf + lc] = ls;
    }
    __syncthreads();
    // merge: thread t -> q = t>>4 (0..31), d = t&15; write AF fragment-major
    {
        const int q = t >> 4, d = t & 15;
        float l = 0.f, a0 = 0.f, a1 = 0.f;
        #pragma unroll
        for (int p = 0; p < 8; ++p) {
            l  += Lw[p][q];
            a0 += Ow[p][q][d];
            a1 += Ow[p][q][16 + d];
        }
        float inv = 1.f / l;
        const int grow = b * NL + m0 + q;
        size_t afb = ((size_t)(grow >> 4) * 8 + h) * 512
                   + (d >> 3) * 128 + (grow & 15) * 8 + (d & 7);
        AF[afb]       = f2bf(a0 * inv);     // col = h*32 + d
        AF[afb + 256] = f2bf(a1 * inv);     // col = h*32 + 16 + d
    }
}

// ---------------------------------------------------------------------------
// rowcol_kernel: per-wave 16x16 tile, K=256, all loads coalesced fragment
// bursts from AF/BF. 384 blocks. Output fp16 row-major for pairwise.
// ---------------------------------------------------------------------------
__global__ __launch_bounds__(256) void rowcol_kernel(
    const ushort* __restrict__ AF, const ushort* __restrict__ BF,
    const float* __restrict__ bc, ushort* __restrict__ rowcol)
{
    const int t = threadIdx.x, lane = t & 63, w = t >> 6;
    const int lg = lane >> 4, lc = lane & 15;
    const int u = blockIdx.x * 4 + w;          // [0,1536)
    const int mb = u >> 4, nb = u & 15;        // m0 = mb*16, n0 = nb*16
    const ushort* afb = AF + (size_t)mb * 8 * 512 + lane * 8;
    const ushort* bfb = BF + (size_t)nb * 8 * 512 + lane * 8;
    bf16x8 a[8], br[8];
    #pragma unroll
    for (int i = 0; i < 8; ++i) {
        a[i]  = *(const bf16x8*)(afb + i * 512);
        br[i] = *(const bf16x8*)(bfb + i * 512);
    }
    f32x4 acc = {};
    #pragma unroll
    for (int i = 0; i < 8; ++i)
        acc = __builtin_amdgcn_mfma_f32_16x16x32_bf16(a[i], br[i], acc, 0, 0, 0);
    const int n = nb * 16 + lc;
    const float bv = bc[n];
    #pragma unroll
    for (int ii = 0; ii < 4; ++ii)
        ((_Float16*)rowcol)[(size_t)(mb * 16 + 4 * lg + ii) * 256 + n] = (_Float16)(acc[ii] + bv);
}

// ---------------------------------------------------------------------------
// pairwise_kernel: grid (12, 24, 2); block tile 32(i) x 64(j), 4 waves 2x2,
// per-lane 2x4 outputs; fp16 addrelu+dot2; broadcast-friendly LDS.
// ---------------------------------------------------------------------------
__global__ __launch_bounds__(256) void pairwise_kernel(
    const ushort* __restrict__ rowcol, const float* __restrict__ w2,
    const float* __restrict__ b2, float* __restrict__ out)
{
    __shared__ __align__(16) ushort rs[32 * 136];
    __shared__ __align__(16) ushort cs[64 * 136];
    __shared__ uint w2u[64];
    const int b = blockIdx.z, i0 = blockIdx.y * 32, j0 = blockIdx.x * 64;
    const int t = threadIdx.x;
    #pragma unroll
    for (int v = t; v < 512; v += 256) {
        int r = v >> 4, q = v & 15;
        *(uint4*)&rs[r * 136 + q * 8] =
            *(const uint4*)(rowcol + (size_t)(b * NL + i0 + r) * 256 + q * 8);
    }
    #pragma unroll
    for (int v = t; v < 1024; v += 256) {
        int r = v >> 4, q = v & 15;
        *(uint4*)&cs[r * 136 + q * 8] =
            *(const uint4*)(rowcol + (size_t)(b * NL + j0 + r) * 256 + 128 + q * 8);
    }
    if (t < 64) {
        float2 wv = *(const float2*)&w2[2 * t];
        h2v hw = {(_Float16)wv.x, (_Float16)wv.y};
        w2u[t] = __builtin_bit_cast(uint, hw);
    }
    __syncthreads();
    const int lane = t & 63, w = t >> 6;
    const int rg = lane >> 3, cg = lane & 7;
    const int wy = w >> 1, wx = w & 1;
    float acc[2][4] = {};
    for (int c8 = 0; c8 < 128; c8 += 8) {
        uint wu[4];
        *(uint4*)wu = *(const uint4*)&w2u[c8 >> 1];
        uint ru[2][4], cu[4][4];
        #pragma unroll
        for (int i = 0; i < 2; ++i)
            *(uint4*)ru[i] = *(const uint4*)&rs[(16 * wy + rg + 8 * i) * 136 + c8];
        #pragma unroll
        for (int j = 0; j < 4; ++j)
            *(uint4*)cu[j] = *(const uint4*)&cs[(32 * wx + cg + 8 * j) * 136 + c8];
        #pragma unroll
        for (int i = 0; i < 2; ++i)
            #pragma unroll
            for (int j = 0; j < 4; ++j) {
                float a = acc[i][j];
                #pragma unroll
                for (int p = 0; p < 4; ++p)
                    a = fdot2u(addrelu2(ru[i][p], cu[j][p]), wu[p], a);
                acc[i][j] = a;
            }
    }
    const float bb = b2[0];
    #pragma unroll
    for (int i = 0; i < 2; ++i)
        #pragma unroll
        for (int j = 0; j < 4; ++j)
            out[(size_t)(b * NL + i0 + 16 * wy + rg + 8 * i) * NL
                + j0 + 32 * wx + cg + 8 * j] = acc[i][j] + bb;
}

// ---------------------------------------------------------------------------
extern "C" void kernel_launch(void* const* d_in, const int* in_sizes, int n_in,
                              void* d_out, int out_size, void* d_ws, size_t ws_size,
                              hipStream_t stream)
{
    const float* features  = (const float*)d_in[0];  // [2,768,256]
    const float* in_proj_w = (const float*)d_in[1];  // [768,256]
    const float* in_proj_b = (const float*)d_in[2];  // [768]
    const float* out_w     = (const float*)d_in[3];  // [256,256]
    const float* out_b     = (const float*)d_in[4];  // [256]
    const float* w1        = (const float*)d_in[5];  // [512,128]
    const float* b1        = (const float*)d_in[6];  // [128]
    const float* w2        = (const float*)d_in[7];  // [128,1]
    const float* b2        = (const float*)d_in[8];  // [1]
    float* out = (float*)d_out;                      // [2,768,768]

    ushort* QF = (ushort*)d_ws;          // 16*48*512 = 393216 u16
    ushort* KF = QF + 393216;            // 393216
    ushort* VF = KF + 393216;            // 16*24*2*512 = 393216
    ushort* AF = VF + 393216;            // 96*8*512 = 393216
    ushort* BF = AF + 393216;            // 16*8*512 = 65536
    float*  bc = (float*)(BF + 65536);   // 256 fp32
    ushort* rowcol = (ushort*)(bc + 256);// [1536,256] fp16

    // 1. qkv projection -> fragment-major QF/KF/VF (+ BF/bc weights)
    front_kernel<<<dim3(353), 512, 0, stream>>>(
        features, in_proj_w, in_proj_b, out_w, out_b, w1, b1, QF, KF, VF, BF, bc);

    // 2. flash attention (coalesced fragment loads) -> AF
    attn_kernel<<<dim3(24, 16), 512, 0, stream>>>(QF, KF, VF, AF);

    // 3. rowcol = attn @ Wc + bc -> fp16 (coalesced fragment loads)
    rowcol_kernel<<<dim3(384), 256, 0, stream>>>(AF, BF, bc, rowcol);

    // 4. pairwise contact MLP (576 blocks)
    pairwise_kernel<<<dim3(12, 24, 2), 256, 0, stream>>>(rowcol, w2, b2, out);
}